// Round 1
// 92.097 us; speedup vs baseline: 1.0477x; 1.0477x over previous
//
#include <hip/hip_runtime.h>
#include <hip/hip_bf16.h>

// B=1024, K(conf)=256, D=1024, P=768.
// 4 launches: prep -> (q|km fused) -> scores -> (softmax+out fused).
// Round 5: latency-hiding restructure. qk: 8 waves/block (2 waves/SIMD),
// scores: 32x32 tiles -> 256 blocks (was 64). Numerics unchanged.

typedef __attribute__((ext_vector_type(8))) short short8;   // 8 bf16
typedef __attribute__((ext_vector_type(4))) float f32x4;    // MFMA acc

__device__ __forceinline__ ushort f2bf(float x) {
    union { float f; uint u; } c; c.f = x;
    return (ushort)((c.u + 0x7FFFu + ((c.u >> 16) & 1u)) >> 16);  // RNE
}
__device__ __forceinline__ float bflo(uint u) {     // bf16 bits in LOW half
    union { uint u; float f; } c; c.u = u << 16; return c.f;
}
__device__ __forceinline__ float bfhi(uint u) {     // bf16 bits in HIGH half
    union { uint u; float f; } c; c.u = u & 0xFFFF0000u; return c.f;
}

// ---------------------------------------------------------------------------
// prep: build all bf16 NT operands (verified round 2).
// ---------------------------------------------------------------------------
__global__ __launch_bounds__(256)
void prep_kernel(const float* __restrict__ J, const float* __restrict__ conf,
                 const float* __restrict__ prior, const float* __restrict__ Wq,
                 const float* __restrict__ Wk,
                 ushort* __restrict__ Jb, ushort* __restrict__ confb,
                 ushort* __restrict__ WqT, ushort* __restrict__ WkT,
                 ushort* __restrict__ cpT)
{
    const int t = threadIdx.x;
    int b = blockIdx.x;

    if (b < 1280) {  // flat convert J, conf
        const float* src; ushort* dst; int base;
        if (b < 1024) { src = J;    dst = Jb;    base = b * 1024; }
        else          { src = conf; dst = confb; base = (b - 1024) * 1024; }
        const float4 v = *(const float4*)(src + base + t * 4);
        ushort4 o;
        o.x = f2bf(v.x); o.y = f2bf(v.y); o.z = f2bf(v.z); o.w = f2bf(v.w);
        *(ushort4*)(dst + base + t * 4) = o;
        return;
    }

    __shared__ float tile[32][33];
    const float* src; ushort* dst; int R, C, tpr; bool usePrior;
    if (b < 2048)      { b -= 1280; src = Wq;   dst = WqT; R = 1024; C = 768;  tpr = 24; usePrior = false; }
    else if (b < 2816) { b -= 2048; src = Wk;   dst = WkT; R = 1024; C = 768;  tpr = 24; usePrior = false; }
    else               { b -= 2816; src = conf; dst = cpT; R = 256;  C = 1024; tpr = 32; usePrior = true;  }
    const int rt = b / tpr, ct = b % tpr;

    {
        const int row = t >> 3, c4 = (t & 7) << 2;
        const float4 v = *(const float4*)(src + (size_t)(rt * 32 + row) * C + ct * 32 + c4);
        const float p = usePrior ? prior[rt * 32 + row] : 1.0f;
        tile[row][c4 + 0] = v.x * p; tile[row][c4 + 1] = v.y * p;
        tile[row][c4 + 2] = v.z * p; tile[row][c4 + 3] = v.w * p;
    }
    __syncthreads();
    {
        const int orow = t >> 3, oc4 = (t & 7) << 2;
        ushort4 o;
        o.x = f2bf(tile[oc4 + 0][orow]); o.y = f2bf(tile[oc4 + 1][orow]);
        o.z = f2bf(tile[oc4 + 2][orow]); o.w = f2bf(tile[oc4 + 3][orow]);
        *(ushort4*)(dst + (size_t)(ct * 32 + orow) * R + rt * 32 + oc4) = o;
    }
}

// ---------------------------------------------------------------------------
// qk: q = Jb @ WqT^T (192 blocks) and km = confb @ WkT^T (48 blocks).
// 64x64 NT tiles, 512 threads = 8 waves -> 2 waves/SIMD for latency hiding.
// Wave w owns a 16x32 sub-tile: wm=(w>>1)*16 (0..48), wn=(w&1)*32.
// ---------------------------------------------------------------------------
__global__ __launch_bounds__(512)
void qk_kernel(const ushort* __restrict__ Jb, const ushort* __restrict__ WqT,
               const ushort* __restrict__ confb, const ushort* __restrict__ WkT,
               ushort* __restrict__ qb, ushort* __restrict__ kmb)
{
    __shared__ __align__(16) ushort As[64][72];
    __shared__ __align__(16) ushort Bs[64][72];

    int bid = blockIdx.x;
    const ushort *A, *B; ushort* C;
    if (bid < 192) { A = Jb; B = WqT; C = qb; }
    else           { bid -= 192; A = confb; B = WkT; C = kmb; }
    const int m0 = (bid / 12) * 64, n0 = (bid % 12) * 64;
    const int N = 768, K = 1024;

    const int t = threadIdx.x;
    const int wave = t >> 6, lane = t & 63;
    const int wm = (wave >> 1) * 16;   // 0,16,32,48
    const int wn = (wave & 1) * 32;    // 0,32
    const int lrow = lane & 15, lko = (lane >> 4) * 8;

    f32x4 acc0 = (f32x4)0.0f, acc1 = (f32x4)0.0f;

    // staging: 64 rows x 64 k, 512 threads -> 1 uint4 per thread per operand
    const int sr = t >> 3, sk = (t & 7) << 3;
    const ushort* Ap = A + (size_t)(m0 + sr) * K + sk;
    const ushort* Bp = B + (size_t)(n0 + sr) * K + sk;
    uint4 av = *(const uint4*)(Ap);
    uint4 bv = *(const uint4*)(Bp);

    for (int k0 = 0; k0 < K; k0 += 64) {
        *(uint4*)&As[sr][sk] = av;
        *(uint4*)&Bs[sr][sk] = bv;
        __syncthreads();
        if (k0 + 64 < K) {
            av = *(const uint4*)(Ap + k0 + 64);
            bv = *(const uint4*)(Bp + k0 + 64);
        }
        #pragma unroll
        for (int kk = 0; kk < 64; kk += 32) {
            const short8 a  = *(const short8*)&As[wm + lrow][kk + lko];
            const short8 b0 = *(const short8*)&Bs[wn + lrow][kk + lko];
            const short8 b1 = *(const short8*)&Bs[wn + 16 + lrow][kk + lko];
            acc0 = __builtin_amdgcn_mfma_f32_16x16x32_bf16(a, b0, acc0, 0, 0, 0);
            acc1 = __builtin_amdgcn_mfma_f32_16x16x32_bf16(a, b1, acc1, 0, 0, 0);
        }
        __syncthreads();
    }

    const int quad = lane >> 4;  // D: row=(lane>>4)*4+reg, col=lane&15
    #pragma unroll
    for (int j = 0; j < 2; ++j) {
        const f32x4 acc = j ? acc1 : acc0;
        #pragma unroll
        for (int r = 0; r < 4; ++r) {
            const int m = m0 + wm + quad * 4 + r;
            const int n = n0 + wn + j * 16 + lrow;
            C[(size_t)m * N + n] = f2bf(acc[r]);
        }
    }
}

// ---------------------------------------------------------------------------
// scores(bf16) = (qb @ kmb^T) / 32   [1024,256]
// 32x32 tiles -> grid (8,32) = 256 blocks (full CU coverage; was 64 blocks).
// 4 waves, each one 16x16 fragment.
// ---------------------------------------------------------------------------
__global__ __launch_bounds__(256)
void scores_kernel(const ushort* __restrict__ qb, const ushort* __restrict__ kmb,
                   ushort* __restrict__ sc)
{
    __shared__ __align__(16) ushort As[32][72];
    __shared__ __align__(16) ushort Bs[32][72];

    const int m0 = blockIdx.y * 32, n0 = blockIdx.x * 32;
    const int t = threadIdx.x;
    const int wave = t >> 6, lane = t & 63;
    const int wm = (wave >> 1) * 16, wn = (wave & 1) * 16;
    const int lrow = lane & 15, lko = (lane >> 4) * 8;

    f32x4 acc = (f32x4)0.0f;

    // staging: 32 rows x 64 k, 256 threads -> 1 uint4 per thread per operand
    const int sr = t >> 3, sk = (t & 7) << 3;
    const ushort* Ap = qb  + (size_t)(m0 + sr) * 768 + sk;
    const ushort* Bp = kmb + (size_t)(n0 + sr) * 768 + sk;
    uint4 av = *(const uint4*)(Ap);
    uint4 bv = *(const uint4*)(Bp);

    for (int k0 = 0; k0 < 768; k0 += 64) {
        *(uint4*)&As[sr][sk] = av;
        *(uint4*)&Bs[sr][sk] = bv;
        __syncthreads();
        if (k0 + 64 < 768) {
            av = *(const uint4*)(Ap + k0 + 64);
            bv = *(const uint4*)(Bp + k0 + 64);
        }
        #pragma unroll
        for (int kk = 0; kk < 64; kk += 32) {
            const short8 a = *(const short8*)&As[wm + lrow][kk + lko];
            const short8 b = *(const short8*)&Bs[wn + lrow][kk + lko];
            acc = __builtin_amdgcn_mfma_f32_16x16x32_bf16(a, b, acc, 0, 0, 0);
        }
        __syncthreads();
    }

    const int quad = lane >> 4;
    #pragma unroll
    for (int r = 0; r < 4; ++r) {
        const int m = m0 + wm + quad * 4 + r;
        const int n = n0 + wn + lrow;
        sc[(size_t)m * 256 + n] = f2bf(acc[r] * 0.03125f);
    }
}

// ---------------------------------------------------------------------------
// out = J + softmax(scores) @ cpT^T.  Grid (16,16), 64x64 out tile, K=256.
// Prologue: per-row softmax of bf16 scores -> unnormalized exp (bf16) in LDS
// as the A-operand; per-row 1/sum applied in the epilogue (exact norm).
// ---------------------------------------------------------------------------
__global__ __launch_bounds__(256)
void out_kernel(const ushort* __restrict__ sc, const ushort* __restrict__ cpT,
                const float* __restrict__ J, float* __restrict__ out)
{
    __shared__ __align__(16) ushort At[64][264];    // exp(scores) bf16, K=256 + pad
    __shared__ __align__(16) ushort Bs[64][72];
    __shared__ float rowInv[64];

    const int t = threadIdx.x;
    const int m0 = blockIdx.y * 64, n0 = blockIdx.x * 64;

    // ---- softmax prologue: 4 threads per row, 64 cols each
    {
        const int row = t >> 2;
        const int cb  = (t & 3) * 64;          // ushort offset in row
        const ushort* srow = sc + (size_t)(m0 + row) * 256 + cb;
        uint4 s[8];
        #pragma unroll
        for (int i = 0; i < 8; ++i) s[i] = *(const uint4*)(srow + i * 8);

        float mx = -1e30f;
        #pragma unroll
        for (int i = 0; i < 8; ++i) {
            mx = fmaxf(mx, fmaxf(fmaxf(bflo(s[i].x), bfhi(s[i].x)),
                                 fmaxf(bflo(s[i].y), bfhi(s[i].y))));
            mx = fmaxf(mx, fmaxf(fmaxf(bflo(s[i].z), bfhi(s[i].z)),
                                 fmaxf(bflo(s[i].w), bfhi(s[i].w))));
        }
        mx = fmaxf(mx, __shfl_xor(mx, 1));
        mx = fmaxf(mx, __shfl_xor(mx, 2));

        float sum = 0.0f;
        #pragma unroll
        for (int i = 0; i < 8; ++i) {
            uint4 o;
            uint* su = (uint*)&s[i];
            uint* ou = (uint*)&o;
            #pragma unroll
            for (int w = 0; w < 4; ++w) {
                const ushort e0 = f2bf(__expf(bflo(su[w]) - mx));
                const ushort e1 = f2bf(__expf(bfhi(su[w]) - mx));
                // BUGFIX (round 3 -> 4): e0/e1 are raw bf16 bits; bflo()
                // already shifts <<16. The extra "<<16" here zeroed the sum
                // -> rowInv = inf -> absmax = inf.
                sum += bflo((uint)e0) + bflo((uint)e1);
                ou[w] = (uint)e0 | ((uint)e1 << 16);
            }
            *(uint4*)&At[row][cb + i * 8] = o;
        }
        sum += __shfl_xor(sum, 1);
        sum += __shfl_xor(sum, 2);
        if ((t & 3) == 0) rowInv[row] = 1.0f / sum;
    }
    __syncthreads();

    // ---- GEMM: out_tile = expS[64,256] @ cpT_tile[64,256]^T
    const int wave = t >> 6, lane = t & 63;
    const int wm = (wave >> 1) * 32, wn = (wave & 1) * 32;
    const int lrow = lane & 15, lko = (lane >> 4) * 8;

    f32x4 acc[2][2];
    #pragma unroll
    for (int i = 0; i < 2; ++i)
        #pragma unroll
        for (int j = 0; j < 2; ++j) acc[i][j] = (f32x4)0.0f;

    const int sr = t >> 2, sk = (t & 3) << 4;
    const ushort* Bp = cpT + (size_t)(n0 + sr) * 256 + sk;
    uint4 bv0 = *(const uint4*)(Bp);
    uint4 bv1 = *(const uint4*)(Bp + 8);

    for (int k0 = 0; k0 < 256; k0 += 64) {
        *(uint4*)&Bs[sr][sk]     = bv0;
        *(uint4*)&Bs[sr][sk + 8] = bv1;
        __syncthreads();
        if (k0 + 64 < 256) {
            bv0 = *(const uint4*)(Bp + k0 + 64);
            bv1 = *(const uint4*)(Bp + k0 + 72);
        }
        #pragma unroll
        for (int kk = 0; kk < 64; kk += 32) {
            const short8 a0 = *(const short8*)&At[wm + lrow][k0 + kk + lko];
            const short8 a1 = *(const short8*)&At[wm + 16 + lrow][k0 + kk + lko];
            const short8 b0 = *(const short8*)&Bs[wn + lrow][kk + lko];
            const short8 b1 = *(const short8*)&Bs[wn + 16 + lrow][kk + lko];
            acc[0][0] = __builtin_amdgcn_mfma_f32_16x16x32_bf16(a0, b0, acc[0][0], 0, 0, 0);
            acc[0][1] = __builtin_amdgcn_mfma_f32_16x16x32_bf16(a0, b1, acc[0][1], 0, 0, 0);
            acc[1][0] = __builtin_amdgcn_mfma_f32_16x16x32_bf16(a1, b0, acc[1][0], 0, 0, 0);
            acc[1][1] = __builtin_amdgcn_mfma_f32_16x16x32_bf16(a1, b1, acc[1][1], 0, 0, 0);
        }
        __syncthreads();
    }

    const int quad = lane >> 4;
    #pragma unroll
    for (int i = 0; i < 2; ++i)
        #pragma unroll
        for (int j = 0; j < 2; ++j)
            #pragma unroll
            for (int r = 0; r < 4; ++r) {
                const int mrel = wm + i * 16 + quad * 4 + r;
                const int m = m0 + mrel;
                const int n = n0 + wn + j * 16 + lrow;
                const size_t off = (size_t)m * 1024 + n;
                out[off] = acc[i][j][r] * rowInv[mrel] + J[off];
            }
}

extern "C" void kernel_launch(void* const* d_in, const int* in_sizes, int n_in,
                              void* d_out, int out_size, void* d_ws, size_t ws_size,
                              hipStream_t stream)
{
    const float* J     = (const float*)d_in[0];
    const float* conf  = (const float*)d_in[1];
    const float* prior = (const float*)d_in[2];
    const float* Wq    = (const float*)d_in[3];
    const float* Wk    = (const float*)d_in[4];
    float* out = (float*)d_out;

    ushort* ws = (ushort*)d_ws;
    ushort* Jb    = ws;                  // 1024*1024
    ushort* confb = Jb    + 1048576;     // 256*1024
    ushort* WqT   = confb + 262144;      // 768*1024
    ushort* WkT   = WqT   + 786432;      // 768*1024
    ushort* cpT   = WkT   + 786432;      // 1024*256
    ushort* qb    = cpT   + 262144;      // 1024*768
    ushort* kmb   = qb    + 786432;      // 256*768
    ushort* scb   = kmb   + 196608;      // 1024*256 bf16 scores

    prep_kernel<<<3072, 256, 0, stream>>>(J, conf, prior, Wq, Wk,
                                          Jb, confb, WqT, WkT, cpT);
    qk_kernel<<<240, 512, 0, stream>>>(Jb, WqT, confb, WkT, qb, kmb);
    scores_kernel<<<dim3(8, 32), 256, 0, stream>>>(qb, kmb, scb);
    out_kernel<<<dim3(16, 16), 256, 0, stream>>>(scb, cpT, J, out);
}